// Round 11
// baseline (1307.957 us; speedup 1.0000x reference)
//
#include <hip/hip_runtime.h>

// SimpleMinkUNet: 5 sparse convs + 4 training-mode BN+ReLU.
// R11: R10 CSR structure kept. pair_gemm fixed: launch_bounds(256,4) caps the
// VGPR blowup (R10: 188 regs / 10% occ from over-pipelined unroll), and PB=2
// pair-pairing shares each (ci) w-quad load across 2 pairs -> w LDS traffic
// halves (the kernel is ds_read-bound, w:f = 4:1).

constexpr int RT = 64;   // output rows per block

struct SegDesc {
    const int* OO[5];
    const int* np[5];
    int*       bs[5];
    int        P[5];
};

// bsT[r][b*27+k] = lower_bound(OO_r[k], min(b*RT, n_out_r)), b in [0,nblk].
// Row b=nblk == real (non-pad) pair count per k.
// Block 0 zeroes the 4KB BN sums region.
__global__ void seg_all_kernel(SegDesc d, int nblk, double* __restrict__ sums)
{
    if (blockIdx.x == 0) {
        sums[threadIdx.x] = 0.0;
        sums[256 + threadIdx.x] = 0.0;
    }
    int idx = blockIdx.x * blockDim.x + threadIdx.x;
    int per = 27 * (nblk + 1);
    if (idx >= 5 * per) return;
    int r   = idx / per;
    int rem = idx - r * per;
    int k   = rem / (nblk + 1);
    int b   = rem - k * (nblk + 1);
    int n_out = *d.np[r];
    int target = b * RT; if (target > n_out) target = n_out;
    const int* ok = d.OO[r] + (size_t)k * d.P[r];
    int lo = 0, hi = d.P[r];
    while (lo < hi) {
        int mid = (lo + hi) >> 1;
        if (ok[mid] < target) lo = mid + 1; else hi = mid;
    }
    d.bs[r][b * 27 + k] = lo;
}

// ---- CSR pass 1: deg[o] counts (convs 1,2,t1,t2) ----
struct CountDesc {
    const int* OO[4];
    const int* bs[4];
    int*       deg[4];
    int        P[4];
    int        off[5];   // cumulative 27*P
};
__global__ __launch_bounds__(256)
void count_all_kernel(CountDesc d, int nblk)
{
    int idx = blockIdx.x * 256 + threadIdx.x;
    if (idx >= d.off[4]) return;
    int r = 0;
    while (r < 3 && idx >= d.off[r + 1]) ++r;
    int rem = idx - d.off[r];
    int k = rem / d.P[r];
    int j = rem - k * d.P[r];
    int len = d.bs[r][nblk * 27 + k];
    if (j < len)
        atomicAdd(&d.deg[r][d.OO[r][(size_t)k * d.P[r] + j]], 1);
}

// ---- CSR pass 2: ptr/fill via wave-scan + one atomic per wave ----
struct AssignDesc {
    int*       degptr[4];   // in: deg; out: start (in place)
    int*       fill[4];
    const int* np[4];
    int*       counter;     // 4 ints, zeroed
};
__global__ __launch_bounds__(256)
void assign_all_kernel(AssignDesc d, int nb)
{
    int r = blockIdx.x / nb;
    int o = (blockIdx.x - r * nb) * 256 + threadIdx.x;
    int n = *d.np[r];
    int* degptr = d.degptr[r];
    int* fill   = d.fill[r];
    int dc = (o < n) ? degptr[o] : 0;
    int lane = threadIdx.x & 63;
    int x = dc;
    #pragma unroll
    for (int ofs = 1; ofs < 64; ofs <<= 1) {
        int y = __shfl_up(x, ofs, 64);
        if (lane >= ofs) x += y;
    }
    int tot = __shfl(x, 63, 64);
    int base = 0;
    if (lane == 63) base = atomicAdd(&d.counter[r], tot);
    base = __shfl(base, 63, 64);
    if (o < n) {
        int start = base + x - dc;
        degptr[o] = start;
        fill[o]   = start;
    }
}

// ---- Phase 1: mini-GEMM per (k, 64-pair chunk); claims CSR slot per pair ----
// PB=2: two pairs share each w-quad load (w dominates LDS traffic 4:1).
template<int CIN, int COUT>
__global__ __launch_bounds__(256, 4)
void pair_gemm_kernel(const float* __restrict__ F, const float* __restrict__ W,
                      const int* __restrict__ II, const int* __restrict__ OO,
                      int P, const int* __restrict__ bs, int nblk,
                      int* __restrict__ fill, float* __restrict__ contrib)
{
    constexpr int CP    = COUT / 4;
    constexpr int NSLOT = 256 / CP;
    constexpr int CH    = CIN / 4;
    constexpr int FS    = CIN + 4;

    __shared__ __align__(16) float s_w[CIN * COUT];
    __shared__ __align__(16) float s_f[64 * FS];
    __shared__ int s_slot[64];

    const int k   = blockIdx.y;
    const int len = bs[nblk * 27 + k];       // real pair count for this k
    const int j0  = blockIdx.x * 64;
    if (j0 >= len) return;
    const int cnt = min(64, len - j0);
    const int tid = threadIdx.x;

    for (int i = tid; i < CIN * COUT / 4; i += 256)
        ((float4*)s_w)[i] = ((const float4*)(W + (size_t)k * CIN * COUT))[i];
    const int* IIk = II + (size_t)k * P + j0;
    for (int i = tid; i < cnt * CH; i += 256) {
        int p = i / CH, q = i - p * CH;
        int in = IIk[p];
        *(float4*)&s_f[p * FS + q * 4] = ((const float4*)(F + (size_t)in * CIN))[q];
    }
    if (tid < cnt) {                         // distinct o within a k -> no contention
        int o = OO[(size_t)k * P + j0 + tid];
        s_slot[tid] = atomicAdd(&fill[o], 1);
    }
    __syncthreads();

    if (tid >= CP * NSLOT) return;
    const int slot = tid / CP;
    const int cq   = (tid % CP) * 4;

    for (int p0 = slot * 2; p0 < cnt; p0 += NSLOT * 2) {
        const int  p1   = p0 + 1;
        const bool has1 = p1 < cnt;
        const int  p1c  = has1 ? p1 : p0;
        float4 a = make_float4(0.f, 0.f, 0.f, 0.f);
        float4 b = make_float4(0.f, 0.f, 0.f, 0.f);
        #pragma unroll
        for (int ci = 0; ci < CIN; ci += 4) {
            float4 w0 = *(const float4*)&s_w[(ci + 0) * COUT + cq];
            float4 w1 = *(const float4*)&s_w[(ci + 1) * COUT + cq];
            float4 w2 = *(const float4*)&s_w[(ci + 2) * COUT + cq];
            float4 w3 = *(const float4*)&s_w[(ci + 3) * COUT + cq];
            float4 f0 = *(const float4*)&s_f[p0  * FS + ci];
            float4 f1 = *(const float4*)&s_f[p1c * FS + ci];
            a.x += f0.x * w0.x + f0.y * w1.x + f0.z * w2.x + f0.w * w3.x;
            a.y += f0.x * w0.y + f0.y * w1.y + f0.z * w2.y + f0.w * w3.y;
            a.z += f0.x * w0.z + f0.y * w1.z + f0.z * w2.z + f0.w * w3.z;
            a.w += f0.x * w0.w + f0.y * w1.w + f0.z * w2.w + f0.w * w3.w;
            b.x += f1.x * w0.x + f1.y * w1.x + f1.z * w2.x + f1.w * w3.x;
            b.y += f1.x * w0.y + f1.y * w1.y + f1.z * w2.y + f1.w * w3.y;
            b.z += f1.x * w0.z + f1.y * w1.z + f1.z * w2.z + f1.w * w3.z;
            b.w += f1.x * w0.w + f1.y * w1.w + f1.z * w2.w + f1.w * w3.w;
        }
        *(float4*)&contrib[(size_t)s_slot[p0] * COUT + cq] = a;
        if (has1)
            *(float4*)&contrib[(size_t)s_slot[p1] * COUT + cq] = b;
    }
}

// ---- Phase 2: stream each output's contiguous contrib run; fused BN ----
template<int COUT, bool BN>
__global__ __launch_bounds__(256)
void gather_reduce_kernel(const float* __restrict__ contrib,
                          const int* __restrict__ ptr_,
                          const int* __restrict__ fill_,
                          const int* __restrict__ n_out_ptr,
                          float* __restrict__ OUT, double* __restrict__ sums)
{
    constexpr int CP = COUT / 4;
    constexpr int NG = 256 / CP;
    constexpr int ROUNDS = (RT + NG - 1) / NG;

    __shared__ float s_bn[BN ? 2 * COUT : 1];

    const int n_out = *n_out_ptr;
    const int row0 = blockIdx.x * RT;
    if (row0 >= n_out) return;
    const int tid = threadIdx.x;
    const int grp = tid / CP;
    const int cq  = (tid % CP) * 4;

    float4 bsum = make_float4(0.f, 0.f, 0.f, 0.f);
    float4 bsq  = make_float4(0.f, 0.f, 0.f, 0.f);

    #pragma unroll
    for (int r = 0; r < ROUNDS; ++r) {
        int og = grp + r * NG;
        int o  = row0 + og;
        if (grp < NG && og < RT && o < n_out) {
            int t0 = ptr_[o], t1 = fill_[o];
            float4 a = make_float4(0.f, 0.f, 0.f, 0.f);
            for (int t = t0; t < t1; ++t) {
                float4 v = *(const float4*)&contrib[(size_t)t * COUT + cq];
                a.x += v.x; a.y += v.y; a.z += v.z; a.w += v.w;
            }
            *(float4*)&OUT[(size_t)o * COUT + cq] = a;
            if (BN) {
                bsum.x += a.x; bsum.y += a.y; bsum.z += a.z; bsum.w += a.w;
                bsq.x += a.x * a.x; bsq.y += a.y * a.y;
                bsq.z += a.z * a.z; bsq.w += a.w * a.w;
            }
        }
    }
    if (BN) {
        if (tid < 2 * COUT) s_bn[tid] = 0.f;
        __syncthreads();
        atomicAdd(&s_bn[cq + 0], bsum.x); atomicAdd(&s_bn[cq + 1], bsum.y);
        atomicAdd(&s_bn[cq + 2], bsum.z); atomicAdd(&s_bn[cq + 3], bsum.w);
        atomicAdd(&s_bn[COUT + cq + 0], bsq.x); atomicAdd(&s_bn[COUT + cq + 1], bsq.y);
        atomicAdd(&s_bn[COUT + cq + 2], bsq.z); atomicAdd(&s_bn[COUT + cq + 3], bsq.w);
        __syncthreads();
        if (tid < COUT) {
            atomicAdd(&sums[tid], (double)s_bn[tid]);
            atomicAdd(&sums[COUT + tid], (double)s_bn[COUT + tid]);
        }
    }
}

// ---- conv0 direct: CIN=4, COUT=16 (flat build + flat pair loop) ----
__device__ __forceinline__ int find_seg(const int* s_off, int p)
{
    int k = 0;
    #pragma unroll
    for (int st = 16; st; st >>= 1)
        if (k + st < 28 && s_off[k + st] <= p) k += st;
    return k;
}

__global__ __launch_bounds__(256)
void sconv0_kernel(const float* __restrict__ F, const float* __restrict__ W,
                   const int* __restrict__ II, const int* __restrict__ OO,
                   int P, const int* __restrict__ n_out_ptr,
                   const int* __restrict__ bs,
                   float* __restrict__ OUT, double* __restrict__ sums)
{
    constexpr int CIN = 4, COUT = 16, CP = 16, NSLOT = 16;

    __shared__ float    s_acc[RT * COUT];
    __shared__ unsigned s_pair[27 * RT];
    __shared__ int s_s[27], s_off[28];

    const int n_out = *n_out_ptr;
    const int row0 = blockIdx.x * RT;
    if (row0 >= n_out) return;
    const int tid = threadIdx.x;

    if (tid < 27) {
        int s = bs[blockIdx.x * 27 + tid];
        int e = bs[(blockIdx.x + 1) * 27 + tid];
        s_s[tid] = s;
        s_off[tid + 1] = e - s;
    }
    if (tid == 0) s_off[0] = 0;
    for (int i = tid; i < RT * COUT; i += 256) s_acc[i] = 0.f;
    __syncthreads();
    if (tid == 0) for (int k = 1; k <= 27; ++k) s_off[k] += s_off[k - 1];
    __syncthreads();
    const int npairs = s_off[27];

    for (int idx = tid; idx < npairs; idx += 256) {
        int k = find_seg(s_off, idx);
        int j = s_s[k] + (idx - s_off[k]);
        int o  = OO[(size_t)k * P + j] - row0;
        int in = II[(size_t)k * P + j];
        s_pair[idx] = ((unsigned)in << 11) | ((unsigned)k << 6) | (unsigned)o;
    }
    __syncthreads();

    const int slot = tid / CP, c = tid % CP;
    for (int p = slot; p < npairs; p += NSLOT) {
        unsigned v = s_pair[p];
        int o = v & 63, k = (v >> 6) & 31;
        float4 f = *(const float4*)(F + (size_t)(v >> 11) * CIN);
        const float* w = W + k * (CIN * COUT) + c;
        float a = f.x * w[0] + f.y * w[COUT] + f.z * w[2 * COUT] + f.w * w[3 * COUT];
        atomicAdd(&s_acc[o * COUT + c], a);
    }
    __syncthreads();

    const int rows = min(RT, n_out - row0);
    {
        const int nel4 = rows * COUT / 4;
        float4* dst = (float4*)(OUT + (size_t)row0 * COUT);
        for (int i = tid; i < nel4; i += 256) dst[i] = ((const float4*)s_acc)[i];
    }
    if (sums != nullptr) {
        float* red = (float*)s_pair;
        const int ch = tid % COUT;
        float s = 0.f, s2 = 0.f;
        for (int r = tid / COUT; r < rows; r += 256 / COUT) {
            float v = s_acc[r * COUT + ch];
            s += v; s2 += v * v;
        }
        red[tid] = s; red[256 + tid] = s2;
        __syncthreads();
        if (tid < COUT) {
            for (int j = tid + COUT; j < 256; j += COUT) { s += red[j]; s2 += red[256 + j]; }
            atomicAdd(&sums[tid], (double)s);
            atomicAdd(&sums[COUT + tid], (double)s2);
        }
    }
}

// ---- direct sconv fallback (R6 structure, bsT layout) ----
template<int CIN, int COUT, int CP, int KS>
__global__ __launch_bounds__(256, 4)
void sconv_direct(const float* __restrict__ F, const float* __restrict__ W,
                  const int* __restrict__ II, const int* __restrict__ OO,
                  int P, const int* __restrict__ n_out_ptr,
                  const int* __restrict__ bs,
                  float* __restrict__ OUT, double* __restrict__ sums)
{
    constexpr int SL    = CP * KS;
    constexpr int NSLOT = 256 / SL;
    constexpr int CINL  = CIN / KS;
    constexpr int NF4   = CINL / 4;

    __shared__ float    s_acc[RT * COUT];
    __shared__ unsigned s_pair[27 * RT];
    __shared__ int s_s[27], s_off[28];

    const int n_out = *n_out_ptr;
    const int row0 = blockIdx.x * RT;
    if (row0 >= n_out) return;
    const int tid = threadIdx.x;

    if (tid < 27) {
        int s = bs[blockIdx.x * 27 + tid];
        int e = bs[(blockIdx.x + 1) * 27 + tid];
        s_s[tid] = s;
        s_off[tid + 1] = e - s;
    }
    if (tid == 0) s_off[0] = 0;
    for (int i = tid; i < RT * COUT; i += 256) s_acc[i] = 0.f;
    __syncthreads();
    if (tid == 0) for (int k = 1; k <= 27; ++k) s_off[k] += s_off[k - 1];
    __syncthreads();
    const int npairs = s_off[27];

    for (int idx = tid; idx < npairs; idx += 256) {
        int k = find_seg(s_off, idx);
        int j = s_s[k] + (idx - s_off[k]);
        int o  = OO[(size_t)k * P + j] - row0;
        int in = II[(size_t)k * P + j];
        s_pair[idx] = ((unsigned)in << 11) | (unsigned)o;
    }
    __syncthreads();

    const int slot = tid / SL;
    const int lc   = tid % CP;
    const int ksub = (tid % SL) / CP;
    const int c    = (CP > COUT && lc >= COUT) ? (COUT - 1) : lc;
    const bool cok = (CP <= COUT) || (lc < COUT);

    for (int k = 0; k < 27; ++k) {
        const int off = s_off[k], end = s_off[k + 1];
        if (off == end) continue;

        float wreg[CINL];
        const float* Wk = W + k * (CIN * COUT) + (ksub * CINL) * COUT + c;
        #pragma unroll
        for (int i = 0; i < CINL; ++i) wreg[i] = Wk[i * COUT];

        for (int base2 = off + 2 * slot; base2 < end; base2 += 2 * NSLOT) {
            unsigned v0 = s_pair[base2];
            const bool has1 = (base2 + 1) < end;
            unsigned v1 = has1 ? s_pair[base2 + 1] : v0;
            const float* F0 = F + (size_t)(v0 >> 11) * CIN + ksub * CINL;
            const float* F1 = F + (size_t)(v1 >> 11) * CIN + ksub * CINL;
            float4 f0[NF4], f1[NF4];
            #pragma unroll
            for (int i = 0; i < NF4; ++i) f0[i] = ((const float4*)F0)[i];
            #pragma unroll
            for (int i = 0; i < NF4; ++i) f1[i] = ((const float4*)F1)[i];
            float a0 = 0.f, a1 = 0.f, a2 = 0.f, a3 = 0.f;
            float b0 = 0.f, b1 = 0.f, b2 = 0.f, b3 = 0.f;
            #pragma unroll
            for (int i = 0; i < NF4; ++i) {
                a0 += f0[i].x * wreg[4*i+0]; a1 += f0[i].y * wreg[4*i+1];
                a2 += f0[i].z * wreg[4*i+2]; a3 += f0[i].w * wreg[4*i+3];
                b0 += f1[i].x * wreg[4*i+0]; b1 += f1[i].y * wreg[4*i+1];
                b2 += f1[i].z * wreg[4*i+2]; b3 += f1[i].w * wreg[4*i+3];
            }
            if (cok) {
                atomicAdd(&s_acc[(v0 & 63) * COUT + c], (a0 + a1) + (a2 + a3));
                if (has1)
                    atomicAdd(&s_acc[(v1 & 63) * COUT + c], (b0 + b1) + (b2 + b3));
            }
        }
    }
    __syncthreads();

    const int rows = min(RT, n_out - row0);
    {
        const int nel4 = rows * COUT / 4;
        float4* dst = (float4*)(OUT + (size_t)row0 * COUT);
        for (int i = tid; i < nel4; i += 256) dst[i] = ((const float4*)s_acc)[i];
    }
    if (sums != nullptr) {
        float* red = (float*)s_pair;
        const int ch = tid % COUT;
        float s = 0.f, s2 = 0.f;
        for (int r = tid / COUT; r < rows; r += 256 / COUT) {
            float v = s_acc[r * COUT + ch];
            s += v; s2 += v * v;
        }
        red[tid] = s; red[256 + tid] = s2;
        __syncthreads();
        if (tid < COUT) {
            for (int j = tid + COUT; j < 256; j += COUT) { s += red[j]; s2 += red[256 + j]; }
            atomicAdd(&sums[tid], (double)s);
            atomicAdd(&sums[COUT + tid], (double)s2);
        }
    }
}

// ---- normalize + ReLU in place ----
template<int COUT>
__global__ void bn_norm_relu_kernel(float* __restrict__ X, const int* __restrict__ n_ptr,
                                    const double* __restrict__ sums,
                                    const float* __restrict__ gamma,
                                    const float* __restrict__ beta)
{
    constexpr int G = 256 / COUT;
    const int n = *n_ptr;
    const int tid = threadIdx.x;
    const int c = tid % COUT;
    const int g = tid / COUT;
    double m  = sums[c] / n;
    double vv = sums[COUT + c] / n - m * m;
    float inv = (float)rsqrt(vv + 1e-5);
    float scale = inv * gamma[c];
    float off = beta[c] - (float)m * scale;
    for (int r = blockIdx.x * G + g; r < n; r += gridDim.x * G) {
        float v = X[r * COUT + c] * scale + off;
        X[r * COUT + c] = v > 0.f ? v : 0.f;
    }
}

extern "C" void kernel_launch(void* const* d_in, const int* in_sizes, int n_in,
                              void* d_out, int out_size, void* d_ws, size_t ws_size,
                              hipStream_t stream)
{
    const float* feats = (const float*)d_in[0];
    const float* W0  = (const float*)d_in[1];
    const float* g0  = (const float*)d_in[2];
    const float* b0  = (const float*)d_in[3];
    const float* W1  = (const float*)d_in[4];
    const float* g1  = (const float*)d_in[5];
    const float* b1  = (const float*)d_in[6];
    const float* W2  = (const float*)d_in[7];
    const float* g2  = (const float*)d_in[8];
    const float* b2  = (const float*)d_in[9];
    const float* Wt1 = (const float*)d_in[10];
    const float* gt1 = (const float*)d_in[11];
    const float* bt1 = (const float*)d_in[12];
    const float* Wt2 = (const float*)d_in[13];
    const int* in0  = (const int*)d_in[14];
    const int* out0 = (const int*)d_in[15];
    const int* in1  = (const int*)d_in[16];
    const int* out1 = (const int*)d_in[17];
    const int* in2  = (const int*)d_in[18];
    const int* out2 = (const int*)d_in[19];
    const int* int1 = (const int*)d_in[20];
    const int* outt1= (const int*)d_in[21];
    const int* int2 = (const int*)d_in[22];
    const int* outt2= (const int*)d_in[23];
    const int* n0p = (const int*)d_in[24];
    const int* n1p = (const int*)d_in[25];
    const int* n2p = (const int*)d_in[26];

    const int n0  = in_sizes[0] / 4;
    const int P0  = in_sizes[14] / 27;
    const int P1  = in_sizes[16] / 27;
    const int P2  = in_sizes[18] / 27;
    const int Pt1 = in_sizes[20] / 27;
    const int Pt2 = in_sizes[22] / 27;

    const int gridC = (n0 + RT - 1) / RT;
    const int nbs = 27 * (gridC + 1);

    char* ws = (char*)d_ws;
    double* sums0  = (double*)(ws + 0);
    double* sums1  = (double*)(ws + 1024);
    double* sums2  = (double*)(ws + 2048);
    double* sumst1 = (double*)(ws + 3072);
    int* counters = (int*)(ws + 4096);
    int* degbase  = (int*)(ws + 4112);
    int* dp1 = degbase, *dp2 = degbase + n0, *dpt1 = degbase + 2*n0, *dpt2 = degbase + 3*n0;
    int* fillbase = degbase + 4 * (size_t)n0;
    int* fl1 = fillbase, *fl2 = fillbase + n0, *flt1 = fillbase + 2*n0, *flt2 = fillbase + 3*n0;
    float* x1  = (float*)(fillbase + 4 * (size_t)n0);
    float* x2  = x1 + (size_t)n0 * 32;
    float* x0  = x2;                       // aliases x2 (dead before x2 written)
    float* xt1 = x1;                       // aliases x1 (dead before xt1 written)
    int* bs0  = (int*)(x2 + (size_t)n0 * 64);
    int* bs1  = bs0 + nbs;
    int* bs2  = bs1 + nbs;
    int* bst1 = bs2 + nbs;
    int* bst2 = bst1 + nbs;
    float* out = (float*)d_out;

    size_t base = (size_t)((char*)(bst2 + nbs) - ws);
    base = (base + 255) & ~(size_t)255;
    float* contrib = (float*)(ws + base);
    size_t avail = (ws_size > base) ? (ws_size - base) : 0;

    auto fits = [&](int P, int C) -> bool {
        return (size_t)27 * P * C * 4 <= avail;
    };
    const bool csr1  = fits(P1, 32);
    const bool csr2  = fits(P2, 64);
    const bool csrt1 = fits(Pt1, 32);
    const bool csrt2 = fits(Pt2, 20);

    hipMemsetAsync(ws + 4096, 0, 16 + (size_t)4 * n0 * 4, stream);

    SegDesc sd;
    sd.OO[0] = out0;  sd.np[0] = n0p; sd.bs[0] = bs0;  sd.P[0] = P0;
    sd.OO[1] = out1;  sd.np[1] = n1p; sd.bs[1] = bs1;  sd.P[1] = P1;
    sd.OO[2] = out2;  sd.np[2] = n2p; sd.bs[2] = bs2;  sd.P[2] = P2;
    sd.OO[3] = outt1; sd.np[3] = n1p; sd.bs[3] = bst1; sd.P[3] = Pt1;
    sd.OO[4] = outt2; sd.np[4] = n0p; sd.bs[4] = bst2; sd.P[4] = Pt2;
    seg_all_kernel<<<(5 * nbs + 255) / 256, 256, 0, stream>>>(sd, gridC, (double*)ws);

    CountDesc cd;
    cd.OO[0] = out1;  cd.bs[0] = bs1;  cd.deg[0] = dp1;  cd.P[0] = P1;
    cd.OO[1] = out2;  cd.bs[1] = bs2;  cd.deg[1] = dp2;  cd.P[1] = P2;
    cd.OO[2] = outt1; cd.bs[2] = bst1; cd.deg[2] = dpt1; cd.P[2] = Pt1;
    cd.OO[3] = outt2; cd.bs[3] = bst2; cd.deg[3] = dpt2; cd.P[3] = Pt2;
    cd.off[0] = 0;
    cd.off[1] = 27 * P1;
    cd.off[2] = cd.off[1] + 27 * P2;
    cd.off[3] = cd.off[2] + 27 * Pt1;
    cd.off[4] = cd.off[3] + 27 * Pt2;
    count_all_kernel<<<(cd.off[4] + 255) / 256, 256, 0, stream>>>(cd, gridC);

    AssignDesc ad;
    ad.degptr[0] = dp1;  ad.fill[0] = fl1;  ad.np[0] = n1p;
    ad.degptr[1] = dp2;  ad.fill[1] = fl2;  ad.np[1] = n2p;
    ad.degptr[2] = dpt1; ad.fill[2] = flt1; ad.np[2] = n1p;
    ad.degptr[3] = dpt2; ad.fill[3] = flt2; ad.np[3] = n0p;
    ad.counter = counters;
    const int nb0 = (n0 + 255) / 256;
    assign_all_kernel<<<4 * nb0, 256, 0, stream>>>(ad, nb0);

    // ---- conv0: 4 -> 16 (direct) ----
    sconv0_kernel<<<gridC, 256, 0, stream>>>(feats, W0, in0, out0, P0, n0p, bs0, x0, sums0);
    bn_norm_relu_kernel<16><<<480, 256, 0, stream>>>(x0, n0p, sums0, g0, b0);

    // ---- conv1: 16 -> 32 ----
    if (csr1) {
        pair_gemm_kernel<16, 32><<<dim3((P1 + 63) / 64, 27), 256, 0, stream>>>(x0, W1, in1, out1, P1, bs1, gridC, fl1, contrib);
        gather_reduce_kernel<32, true><<<gridC, 256, 0, stream>>>(contrib, dp1, fl1, n1p, x1, sums1);
    } else {
        sconv_direct<16, 32, 32, 1><<<gridC, 256, 0, stream>>>(x0, W1, in1, out1, P1, n1p, bs1, x1, sums1);
    }
    bn_norm_relu_kernel<32><<<480, 256, 0, stream>>>(x1, n1p, sums1, g1, b1);

    // ---- conv2: 32 -> 64 ----
    if (csr2) {
        pair_gemm_kernel<32, 64><<<dim3((P2 + 63) / 64, 27), 256, 0, stream>>>(x1, W2, in2, out2, P2, bs2, gridC, fl2, contrib);
        gather_reduce_kernel<64, true><<<gridC, 256, 0, stream>>>(contrib, dp2, fl2, n2p, x2, sums2);
    } else {
        sconv_direct<32, 64, 64, 1><<<gridC, 256, 0, stream>>>(x1, W2, in2, out2, P2, n2p, bs2, x2, sums2);
    }
    bn_norm_relu_kernel<64><<<480, 256, 0, stream>>>(x2, n2p, sums2, g2, b2);

    // ---- convtr1: 64 -> 32 ----
    if (csrt1) {
        pair_gemm_kernel<64, 32><<<dim3((Pt1 + 63) / 64, 27), 256, 0, stream>>>(x2, Wt1, int1, outt1, Pt1, bst1, gridC, flt1, contrib);
        gather_reduce_kernel<32, true><<<gridC, 256, 0, stream>>>(contrib, dpt1, flt1, n1p, xt1, sumst1);
    } else {
        sconv_direct<64, 32, 32, 2><<<gridC, 256, 0, stream>>>(x2, Wt1, int1, outt1, Pt1, n1p, bst1, xt1, sumst1);
    }
    bn_norm_relu_kernel<32><<<480, 256, 0, stream>>>(xt1, n1p, sumst1, gt1, bt1);

    // ---- convtr2: 32 -> 20, no BN ----
    if (csrt2) {
        pair_gemm_kernel<32, 20><<<dim3((Pt2 + 63) / 64, 27), 256, 0, stream>>>(xt1, Wt2, int2, outt2, Pt2, bst2, gridC, flt2, contrib);
        gather_reduce_kernel<20, false><<<gridC, 256, 0, stream>>>(contrib, dpt2, flt2, n0p, out, nullptr);
    } else {
        sconv_direct<32, 20, 32, 1><<<gridC, 256, 0, stream>>>(xt1, Wt2, int2, outt2, Pt2, n0p, bst2, out, nullptr);
    }
}

// Round 12
// 595.865 us; speedup vs baseline: 2.1951x; 2.1951x over previous
//
#include <hip/hip_runtime.h>

// SimpleMinkUNet: 5 sparse convs + 4 training-mode BN+ReLU.
// R12: R10 CSR structure. pair_gemm: PB=2 (w-quad shared across 2 pairs;
// w:f LDS traffic was 4:1) + plain launch_bounds(256) + "#pragma unroll 4"
// on the ci loop. R10 (no bound, full unroll) -> 188 VGPR / 10% occ;
// R11 (min-waves bound) -> VGPR squeezed to 64 -> scratch spill (WRITE 1.1GB,
// HBM 50%). Partial unroll bounds the pipelining window at the source.

constexpr int RT = 64;   // output rows per block

struct SegDesc {
    const int* OO[5];
    const int* np[5];
    int*       bs[5];
    int        P[5];
};

// bsT[r][b*27+k] = lower_bound(OO_r[k], min(b*RT, n_out_r)), b in [0,nblk].
// Row b=nblk == real (non-pad) pair count per k.
// Block 0 zeroes the 4KB BN sums region.
__global__ void seg_all_kernel(SegDesc d, int nblk, double* __restrict__ sums)
{
    if (blockIdx.x == 0) {
        sums[threadIdx.x] = 0.0;
        sums[256 + threadIdx.x] = 0.0;
    }
    int idx = blockIdx.x * blockDim.x + threadIdx.x;
    int per = 27 * (nblk + 1);
    if (idx >= 5 * per) return;
    int r   = idx / per;
    int rem = idx - r * per;
    int k   = rem / (nblk + 1);
    int b   = rem - k * (nblk + 1);
    int n_out = *d.np[r];
    int target = b * RT; if (target > n_out) target = n_out;
    const int* ok = d.OO[r] + (size_t)k * d.P[r];
    int lo = 0, hi = d.P[r];
    while (lo < hi) {
        int mid = (lo + hi) >> 1;
        if (ok[mid] < target) lo = mid + 1; else hi = mid;
    }
    d.bs[r][b * 27 + k] = lo;
}

// ---- CSR pass 1: deg[o] counts (convs 1,2,t1,t2) ----
struct CountDesc {
    const int* OO[4];
    const int* bs[4];
    int*       deg[4];
    int        P[4];
    int        off[5];   // cumulative 27*P
};
__global__ __launch_bounds__(256)
void count_all_kernel(CountDesc d, int nblk)
{
    int idx = blockIdx.x * 256 + threadIdx.x;
    if (idx >= d.off[4]) return;
    int r = 0;
    while (r < 3 && idx >= d.off[r + 1]) ++r;
    int rem = idx - d.off[r];
    int k = rem / d.P[r];
    int j = rem - k * d.P[r];
    int len = d.bs[r][nblk * 27 + k];
    if (j < len)
        atomicAdd(&d.deg[r][d.OO[r][(size_t)k * d.P[r] + j]], 1);
}

// ---- CSR pass 2: ptr/fill via wave-scan + one atomic per wave ----
struct AssignDesc {
    int*       degptr[4];   // in: deg; out: start (in place)
    int*       fill[4];
    const int* np[4];
    int*       counter;     // 4 ints, zeroed
};
__global__ __launch_bounds__(256)
void assign_all_kernel(AssignDesc d, int nb)
{
    int r = blockIdx.x / nb;
    int o = (blockIdx.x - r * nb) * 256 + threadIdx.x;
    int n = *d.np[r];
    int* degptr = d.degptr[r];
    int* fill   = d.fill[r];
    int dc = (o < n) ? degptr[o] : 0;
    int lane = threadIdx.x & 63;
    int x = dc;
    #pragma unroll
    for (int ofs = 1; ofs < 64; ofs <<= 1) {
        int y = __shfl_up(x, ofs, 64);
        if (lane >= ofs) x += y;
    }
    int tot = __shfl(x, 63, 64);
    int base = 0;
    if (lane == 63) base = atomicAdd(&d.counter[r], tot);
    base = __shfl(base, 63, 64);
    if (o < n) {
        int start = base + x - dc;
        degptr[o] = start;
        fill[o]   = start;
    }
}

// ---- Phase 1: mini-GEMM per (k, 64-pair chunk); claims CSR slot per pair ----
// PB=2 shares each w-quad across 2 pairs; unroll 4 bounds register pressure.
template<int CIN, int COUT>
__global__ __launch_bounds__(256)
void pair_gemm_kernel(const float* __restrict__ F, const float* __restrict__ W,
                      const int* __restrict__ II, const int* __restrict__ OO,
                      int P, const int* __restrict__ bs, int nblk,
                      int* __restrict__ fill, float* __restrict__ contrib)
{
    constexpr int CP    = COUT / 4;
    constexpr int NSLOT = 256 / CP;
    constexpr int CH    = CIN / 4;
    constexpr int FS    = CIN + 4;

    __shared__ __align__(16) float s_w[CIN * COUT];
    __shared__ __align__(16) float s_f[64 * FS];
    __shared__ int s_slot[64];

    const int k   = blockIdx.y;
    const int len = bs[nblk * 27 + k];       // real pair count for this k
    const int j0  = blockIdx.x * 64;
    if (j0 >= len) return;
    const int cnt = min(64, len - j0);
    const int tid = threadIdx.x;

    for (int i = tid; i < CIN * COUT / 4; i += 256)
        ((float4*)s_w)[i] = ((const float4*)(W + (size_t)k * CIN * COUT))[i];
    const int* IIk = II + (size_t)k * P + j0;
    for (int i = tid; i < cnt * CH; i += 256) {
        int p = i / CH, q = i - p * CH;
        int in = IIk[p];
        *(float4*)&s_f[p * FS + q * 4] = ((const float4*)(F + (size_t)in * CIN))[q];
    }
    if (tid < cnt) {                         // distinct o within a k -> no contention
        int o = OO[(size_t)k * P + j0 + tid];
        s_slot[tid] = atomicAdd(&fill[o], 1);
    }
    __syncthreads();

    if (tid >= CP * NSLOT) return;
    const int slot = tid / CP;
    const int cq   = (tid % CP) * 4;

    for (int p0 = slot * 2; p0 < cnt; p0 += NSLOT * 2) {
        const int  p1   = p0 + 1;
        const bool has1 = p1 < cnt;
        const int  p1c  = has1 ? p1 : p0;
        float4 a = make_float4(0.f, 0.f, 0.f, 0.f);
        float4 b = make_float4(0.f, 0.f, 0.f, 0.f);
        #pragma unroll 4
        for (int ci = 0; ci < CIN; ci += 4) {
            float4 w0 = *(const float4*)&s_w[(ci + 0) * COUT + cq];
            float4 w1 = *(const float4*)&s_w[(ci + 1) * COUT + cq];
            float4 w2 = *(const float4*)&s_w[(ci + 2) * COUT + cq];
            float4 w3 = *(const float4*)&s_w[(ci + 3) * COUT + cq];
            float4 f0 = *(const float4*)&s_f[p0  * FS + ci];
            float4 f1 = *(const float4*)&s_f[p1c * FS + ci];
            a.x += f0.x * w0.x + f0.y * w1.x + f0.z * w2.x + f0.w * w3.x;
            a.y += f0.x * w0.y + f0.y * w1.y + f0.z * w2.y + f0.w * w3.y;
            a.z += f0.x * w0.z + f0.y * w1.z + f0.z * w2.z + f0.w * w3.z;
            a.w += f0.x * w0.w + f0.y * w1.w + f0.z * w2.w + f0.w * w3.w;
            b.x += f1.x * w0.x + f1.y * w1.x + f1.z * w2.x + f1.w * w3.x;
            b.y += f1.x * w0.y + f1.y * w1.y + f1.z * w2.y + f1.w * w3.y;
            b.z += f1.x * w0.z + f1.y * w1.z + f1.z * w2.z + f1.w * w3.z;
            b.w += f1.x * w0.w + f1.y * w1.w + f1.z * w2.w + f1.w * w3.w;
        }
        *(float4*)&contrib[(size_t)s_slot[p0] * COUT + cq] = a;
        if (has1)
            *(float4*)&contrib[(size_t)s_slot[p1] * COUT + cq] = b;
    }
}

// ---- Phase 2: stream each output's contiguous contrib run; fused BN ----
template<int COUT, bool BN>
__global__ __launch_bounds__(256)
void gather_reduce_kernel(const float* __restrict__ contrib,
                          const int* __restrict__ ptr_,
                          const int* __restrict__ fill_,
                          const int* __restrict__ n_out_ptr,
                          float* __restrict__ OUT, double* __restrict__ sums)
{
    constexpr int CP = COUT / 4;
    constexpr int NG = 256 / CP;
    constexpr int ROUNDS = (RT + NG - 1) / NG;

    __shared__ float s_bn[BN ? 2 * COUT : 1];

    const int n_out = *n_out_ptr;
    const int row0 = blockIdx.x * RT;
    if (row0 >= n_out) return;
    const int tid = threadIdx.x;
    const int grp = tid / CP;
    const int cq  = (tid % CP) * 4;

    float4 bsum = make_float4(0.f, 0.f, 0.f, 0.f);
    float4 bsq  = make_float4(0.f, 0.f, 0.f, 0.f);

    #pragma unroll
    for (int r = 0; r < ROUNDS; ++r) {
        int og = grp + r * NG;
        int o  = row0 + og;
        if (grp < NG && og < RT && o < n_out) {
            int t0 = ptr_[o], t1 = fill_[o];
            float4 a = make_float4(0.f, 0.f, 0.f, 0.f);
            for (int t = t0; t < t1; ++t) {
                float4 v = *(const float4*)&contrib[(size_t)t * COUT + cq];
                a.x += v.x; a.y += v.y; a.z += v.z; a.w += v.w;
            }
            *(float4*)&OUT[(size_t)o * COUT + cq] = a;
            if (BN) {
                bsum.x += a.x; bsum.y += a.y; bsum.z += a.z; bsum.w += a.w;
                bsq.x += a.x * a.x; bsq.y += a.y * a.y;
                bsq.z += a.z * a.z; bsq.w += a.w * a.w;
            }
        }
    }
    if (BN) {
        if (tid < 2 * COUT) s_bn[tid] = 0.f;
        __syncthreads();
        atomicAdd(&s_bn[cq + 0], bsum.x); atomicAdd(&s_bn[cq + 1], bsum.y);
        atomicAdd(&s_bn[cq + 2], bsum.z); atomicAdd(&s_bn[cq + 3], bsum.w);
        atomicAdd(&s_bn[COUT + cq + 0], bsq.x); atomicAdd(&s_bn[COUT + cq + 1], bsq.y);
        atomicAdd(&s_bn[COUT + cq + 2], bsq.z); atomicAdd(&s_bn[COUT + cq + 3], bsq.w);
        __syncthreads();
        if (tid < COUT) {
            atomicAdd(&sums[tid], (double)s_bn[tid]);
            atomicAdd(&sums[COUT + tid], (double)s_bn[COUT + tid]);
        }
    }
}

// ---- conv0 direct: CIN=4, COUT=16 (flat build + flat pair loop) ----
__device__ __forceinline__ int find_seg(const int* s_off, int p)
{
    int k = 0;
    #pragma unroll
    for (int st = 16; st; st >>= 1)
        if (k + st < 28 && s_off[k + st] <= p) k += st;
    return k;
}

__global__ __launch_bounds__(256)
void sconv0_kernel(const float* __restrict__ F, const float* __restrict__ W,
                   const int* __restrict__ II, const int* __restrict__ OO,
                   int P, const int* __restrict__ n_out_ptr,
                   const int* __restrict__ bs,
                   float* __restrict__ OUT, double* __restrict__ sums)
{
    constexpr int CIN = 4, COUT = 16, CP = 16, NSLOT = 16;

    __shared__ float    s_acc[RT * COUT];
    __shared__ unsigned s_pair[27 * RT];
    __shared__ int s_s[27], s_off[28];

    const int n_out = *n_out_ptr;
    const int row0 = blockIdx.x * RT;
    if (row0 >= n_out) return;
    const int tid = threadIdx.x;

    if (tid < 27) {
        int s = bs[blockIdx.x * 27 + tid];
        int e = bs[(blockIdx.x + 1) * 27 + tid];
        s_s[tid] = s;
        s_off[tid + 1] = e - s;
    }
    if (tid == 0) s_off[0] = 0;
    for (int i = tid; i < RT * COUT; i += 256) s_acc[i] = 0.f;
    __syncthreads();
    if (tid == 0) for (int k = 1; k <= 27; ++k) s_off[k] += s_off[k - 1];
    __syncthreads();
    const int npairs = s_off[27];

    for (int idx = tid; idx < npairs; idx += 256) {
        int k = find_seg(s_off, idx);
        int j = s_s[k] + (idx - s_off[k]);
        int o  = OO[(size_t)k * P + j] - row0;
        int in = II[(size_t)k * P + j];
        s_pair[idx] = ((unsigned)in << 11) | ((unsigned)k << 6) | (unsigned)o;
    }
    __syncthreads();

    const int slot = tid / CP, c = tid % CP;
    for (int p = slot; p < npairs; p += NSLOT) {
        unsigned v = s_pair[p];
        int o = v & 63, k = (v >> 6) & 31;
        float4 f = *(const float4*)(F + (size_t)(v >> 11) * CIN);
        const float* w = W + k * (CIN * COUT) + c;
        float a = f.x * w[0] + f.y * w[COUT] + f.z * w[2 * COUT] + f.w * w[3 * COUT];
        atomicAdd(&s_acc[o * COUT + c], a);
    }
    __syncthreads();

    const int rows = min(RT, n_out - row0);
    {
        const int nel4 = rows * COUT / 4;
        float4* dst = (float4*)(OUT + (size_t)row0 * COUT);
        for (int i = tid; i < nel4; i += 256) dst[i] = ((const float4*)s_acc)[i];
    }
    if (sums != nullptr) {
        float* red = (float*)s_pair;
        const int ch = tid % COUT;
        float s = 0.f, s2 = 0.f;
        for (int r = tid / COUT; r < rows; r += 256 / COUT) {
            float v = s_acc[r * COUT + ch];
            s += v; s2 += v * v;
        }
        red[tid] = s; red[256 + tid] = s2;
        __syncthreads();
        if (tid < COUT) {
            for (int j = tid + COUT; j < 256; j += COUT) { s += red[j]; s2 += red[256 + j]; }
            atomicAdd(&sums[tid], (double)s);
            atomicAdd(&sums[COUT + tid], (double)s2);
        }
    }
}

// ---- direct sconv fallback (R6 structure, bsT layout) ----
template<int CIN, int COUT, int CP, int KS>
__global__ __launch_bounds__(256, 4)
void sconv_direct(const float* __restrict__ F, const float* __restrict__ W,
                  const int* __restrict__ II, const int* __restrict__ OO,
                  int P, const int* __restrict__ n_out_ptr,
                  const int* __restrict__ bs,
                  float* __restrict__ OUT, double* __restrict__ sums)
{
    constexpr int SL    = CP * KS;
    constexpr int NSLOT = 256 / SL;
    constexpr int CINL  = CIN / KS;
    constexpr int NF4   = CINL / 4;

    __shared__ float    s_acc[RT * COUT];
    __shared__ unsigned s_pair[27 * RT];
    __shared__ int s_s[27], s_off[28];

    const int n_out = *n_out_ptr;
    const int row0 = blockIdx.x * RT;
    if (row0 >= n_out) return;
    const int tid = threadIdx.x;

    if (tid < 27) {
        int s = bs[blockIdx.x * 27 + tid];
        int e = bs[(blockIdx.x + 1) * 27 + tid];
        s_s[tid] = s;
        s_off[tid + 1] = e - s;
    }
    if (tid == 0) s_off[0] = 0;
    for (int i = tid; i < RT * COUT; i += 256) s_acc[i] = 0.f;
    __syncthreads();
    if (tid == 0) for (int k = 1; k <= 27; ++k) s_off[k] += s_off[k - 1];
    __syncthreads();
    const int npairs = s_off[27];

    for (int idx = tid; idx < npairs; idx += 256) {
        int k = find_seg(s_off, idx);
        int j = s_s[k] + (idx - s_off[k]);
        int o  = OO[(size_t)k * P + j] - row0;
        int in = II[(size_t)k * P + j];
        s_pair[idx] = ((unsigned)in << 11) | (unsigned)o;
    }
    __syncthreads();

    const int slot = tid / SL;
    const int lc   = tid % CP;
    const int ksub = (tid % SL) / CP;
    const int c    = (CP > COUT && lc >= COUT) ? (COUT - 1) : lc;
    const bool cok = (CP <= COUT) || (lc < COUT);

    for (int k = 0; k < 27; ++k) {
        const int off = s_off[k], end = s_off[k + 1];
        if (off == end) continue;

        float wreg[CINL];
        const float* Wk = W + k * (CIN * COUT) + (ksub * CINL) * COUT + c;
        #pragma unroll
        for (int i = 0; i < CINL; ++i) wreg[i] = Wk[i * COUT];

        for (int base2 = off + 2 * slot; base2 < end; base2 += 2 * NSLOT) {
            unsigned v0 = s_pair[base2];
            const bool has1 = (base2 + 1) < end;
            unsigned v1 = has1 ? s_pair[base2 + 1] : v0;
            const float* F0 = F + (size_t)(v0 >> 11) * CIN + ksub * CINL;
            const float* F1 = F + (size_t)(v1 >> 11) * CIN + ksub * CINL;
            float4 f0[NF4], f1[NF4];
            #pragma unroll
            for (int i = 0; i < NF4; ++i) f0[i] = ((const float4*)F0)[i];
            #pragma unroll
            for (int i = 0; i < NF4; ++i) f1[i] = ((const float4*)F1)[i];
            float a0 = 0.f, a1 = 0.f, a2 = 0.f, a3 = 0.f;
            float b0 = 0.f, b1 = 0.f, b2 = 0.f, b3 = 0.f;
            #pragma unroll
            for (int i = 0; i < NF4; ++i) {
                a0 += f0[i].x * wreg[4*i+0]; a1 += f0[i].y * wreg[4*i+1];
                a2 += f0[i].z * wreg[4*i+2]; a3 += f0[i].w * wreg[4*i+3];
                b0 += f1[i].x * wreg[4*i+0]; b1 += f1[i].y * wreg[4*i+1];
                b2 += f1[i].z * wreg[4*i+2]; b3 += f1[i].w * wreg[4*i+3];
            }
            if (cok) {
                atomicAdd(&s_acc[(v0 & 63) * COUT + c], (a0 + a1) + (a2 + a3));
                if (has1)
                    atomicAdd(&s_acc[(v1 & 63) * COUT + c], (b0 + b1) + (b2 + b3));
            }
        }
    }
    __syncthreads();

    const int rows = min(RT, n_out - row0);
    {
        const int nel4 = rows * COUT / 4;
        float4* dst = (float4*)(OUT + (size_t)row0 * COUT);
        for (int i = tid; i < nel4; i += 256) dst[i] = ((const float4*)s_acc)[i];
    }
    if (sums != nullptr) {
        float* red = (float*)s_pair;
        const int ch = tid % COUT;
        float s = 0.f, s2 = 0.f;
        for (int r = tid / COUT; r < rows; r += 256 / COUT) {
            float v = s_acc[r * COUT + ch];
            s += v; s2 += v * v;
        }
        red[tid] = s; red[256 + tid] = s2;
        __syncthreads();
        if (tid < COUT) {
            for (int j = tid + COUT; j < 256; j += COUT) { s += red[j]; s2 += red[256 + j]; }
            atomicAdd(&sums[tid], (double)s);
            atomicAdd(&sums[COUT + tid], (double)s2);
        }
    }
}

// ---- normalize + ReLU in place ----
template<int COUT>
__global__ void bn_norm_relu_kernel(float* __restrict__ X, const int* __restrict__ n_ptr,
                                    const double* __restrict__ sums,
                                    const float* __restrict__ gamma,
                                    const float* __restrict__ beta)
{
    constexpr int G = 256 / COUT;
    const int n = *n_ptr;
    const int tid = threadIdx.x;
    const int c = tid % COUT;
    const int g = tid / COUT;
    double m  = sums[c] / n;
    double vv = sums[COUT + c] / n - m * m;
    float inv = (float)rsqrt(vv + 1e-5);
    float scale = inv * gamma[c];
    float off = beta[c] - (float)m * scale;
    for (int r = blockIdx.x * G + g; r < n; r += gridDim.x * G) {
        float v = X[r * COUT + c] * scale + off;
        X[r * COUT + c] = v > 0.f ? v : 0.f;
    }
}

extern "C" void kernel_launch(void* const* d_in, const int* in_sizes, int n_in,
                              void* d_out, int out_size, void* d_ws, size_t ws_size,
                              hipStream_t stream)
{
    const float* feats = (const float*)d_in[0];
    const float* W0  = (const float*)d_in[1];
    const float* g0  = (const float*)d_in[2];
    const float* b0  = (const float*)d_in[3];
    const float* W1  = (const float*)d_in[4];
    const float* g1  = (const float*)d_in[5];
    const float* b1  = (const float*)d_in[6];
    const float* W2  = (const float*)d_in[7];
    const float* g2  = (const float*)d_in[8];
    const float* b2  = (const float*)d_in[9];
    const float* Wt1 = (const float*)d_in[10];
    const float* gt1 = (const float*)d_in[11];
    const float* bt1 = (const float*)d_in[12];
    const float* Wt2 = (const float*)d_in[13];
    const int* in0  = (const int*)d_in[14];
    const int* out0 = (const int*)d_in[15];
    const int* in1  = (const int*)d_in[16];
    const int* out1 = (const int*)d_in[17];
    const int* in2  = (const int*)d_in[18];
    const int* out2 = (const int*)d_in[19];
    const int* int1 = (const int*)d_in[20];
    const int* outt1= (const int*)d_in[21];
    const int* int2 = (const int*)d_in[22];
    const int* outt2= (const int*)d_in[23];
    const int* n0p = (const int*)d_in[24];
    const int* n1p = (const int*)d_in[25];
    const int* n2p = (const int*)d_in[26];

    const int n0  = in_sizes[0] / 4;
    const int P0  = in_sizes[14] / 27;
    const int P1  = in_sizes[16] / 27;
    const int P2  = in_sizes[18] / 27;
    const int Pt1 = in_sizes[20] / 27;
    const int Pt2 = in_sizes[22] / 27;

    const int gridC = (n0 + RT - 1) / RT;
    const int nbs = 27 * (gridC + 1);

    char* ws = (char*)d_ws;
    double* sums0  = (double*)(ws + 0);
    double* sums1  = (double*)(ws + 1024);
    double* sums2  = (double*)(ws + 2048);
    double* sumst1 = (double*)(ws + 3072);
    int* counters = (int*)(ws + 4096);
    int* degbase  = (int*)(ws + 4112);
    int* dp1 = degbase, *dp2 = degbase + n0, *dpt1 = degbase + 2*n0, *dpt2 = degbase + 3*n0;
    int* fillbase = degbase + 4 * (size_t)n0;
    int* fl1 = fillbase, *fl2 = fillbase + n0, *flt1 = fillbase + 2*n0, *flt2 = fillbase + 3*n0;
    float* x1  = (float*)(fillbase + 4 * (size_t)n0);
    float* x2  = x1 + (size_t)n0 * 32;
    float* x0  = x2;                       // aliases x2 (dead before x2 written)
    float* xt1 = x1;                       // aliases x1 (dead before xt1 written)
    int* bs0  = (int*)(x2 + (size_t)n0 * 64);
    int* bs1  = bs0 + nbs;
    int* bs2  = bs1 + nbs;
    int* bst1 = bs2 + nbs;
    int* bst2 = bst1 + nbs;
    float* out = (float*)d_out;

    size_t base = (size_t)((char*)(bst2 + nbs) - ws);
    base = (base + 255) & ~(size_t)255;
    float* contrib = (float*)(ws + base);
    size_t avail = (ws_size > base) ? (ws_size - base) : 0;

    auto fits = [&](int P, int C) -> bool {
        return (size_t)27 * P * C * 4 <= avail;
    };
    const bool csr1  = fits(P1, 32);
    const bool csr2  = fits(P2, 64);
    const bool csrt1 = fits(Pt1, 32);
    const bool csrt2 = fits(Pt2, 20);

    hipMemsetAsync(ws + 4096, 0, 16 + (size_t)4 * n0 * 4, stream);

    SegDesc sd;
    sd.OO[0] = out0;  sd.np[0] = n0p; sd.bs[0] = bs0;  sd.P[0] = P0;
    sd.OO[1] = out1;  sd.np[1] = n1p; sd.bs[1] = bs1;  sd.P[1] = P1;
    sd.OO[2] = out2;  sd.np[2] = n2p; sd.bs[2] = bs2;  sd.P[2] = P2;
    sd.OO[3] = outt1; sd.np[3] = n1p; sd.bs[3] = bst1; sd.P[3] = Pt1;
    sd.OO[4] = outt2; sd.np[4] = n0p; sd.bs[4] = bst2; sd.P[4] = Pt2;
    seg_all_kernel<<<(5 * nbs + 255) / 256, 256, 0, stream>>>(sd, gridC, (double*)ws);

    CountDesc cd;
    cd.OO[0] = out1;  cd.bs[0] = bs1;  cd.deg[0] = dp1;  cd.P[0] = P1;
    cd.OO[1] = out2;  cd.bs[1] = bs2;  cd.deg[1] = dp2;  cd.P[1] = P2;
    cd.OO[2] = outt1; cd.bs[2] = bst1; cd.deg[2] = dpt1; cd.P[2] = Pt1;
    cd.OO[3] = outt2; cd.bs[3] = bst2; cd.deg[3] = dpt2; cd.P[3] = Pt2;
    cd.off[0] = 0;
    cd.off[1] = 27 * P1;
    cd.off[2] = cd.off[1] + 27 * P2;
    cd.off[3] = cd.off[2] + 27 * Pt1;
    cd.off[4] = cd.off[3] + 27 * Pt2;
    count_all_kernel<<<(cd.off[4] + 255) / 256, 256, 0, stream>>>(cd, gridC);

    AssignDesc ad;
    ad.degptr[0] = dp1;  ad.fill[0] = fl1;  ad.np[0] = n1p;
    ad.degptr[1] = dp2;  ad.fill[1] = fl2;  ad.np[1] = n2p;
    ad.degptr[2] = dpt1; ad.fill[2] = flt1; ad.np[2] = n1p;
    ad.degptr[3] = dpt2; ad.fill[3] = flt2; ad.np[3] = n0p;
    ad.counter = counters;
    const int nb0 = (n0 + 255) / 256;
    assign_all_kernel<<<4 * nb0, 256, 0, stream>>>(ad, nb0);

    // ---- conv0: 4 -> 16 (direct) ----
    sconv0_kernel<<<gridC, 256, 0, stream>>>(feats, W0, in0, out0, P0, n0p, bs0, x0, sums0);
    bn_norm_relu_kernel<16><<<480, 256, 0, stream>>>(x0, n0p, sums0, g0, b0);

    // ---- conv1: 16 -> 32 ----
    if (csr1) {
        pair_gemm_kernel<16, 32><<<dim3((P1 + 63) / 64, 27), 256, 0, stream>>>(x0, W1, in1, out1, P1, bs1, gridC, fl1, contrib);
        gather_reduce_kernel<32, true><<<gridC, 256, 0, stream>>>(contrib, dp1, fl1, n1p, x1, sums1);
    } else {
        sconv_direct<16, 32, 32, 1><<<gridC, 256, 0, stream>>>(x0, W1, in1, out1, P1, n1p, bs1, x1, sums1);
    }
    bn_norm_relu_kernel<32><<<480, 256, 0, stream>>>(x1, n1p, sums1, g1, b1);

    // ---- conv2: 32 -> 64 ----
    if (csr2) {
        pair_gemm_kernel<32, 64><<<dim3((P2 + 63) / 64, 27), 256, 0, stream>>>(x1, W2, in2, out2, P2, bs2, gridC, fl2, contrib);
        gather_reduce_kernel<64, true><<<gridC, 256, 0, stream>>>(contrib, dp2, fl2, n2p, x2, sums2);
    } else {
        sconv_direct<32, 64, 64, 1><<<gridC, 256, 0, stream>>>(x1, W2, in2, out2, P2, n2p, bs2, x2, sums2);
    }
    bn_norm_relu_kernel<64><<<480, 256, 0, stream>>>(x2, n2p, sums2, g2, b2);

    // ---- convtr1: 64 -> 32 ----
    if (csrt1) {
        pair_gemm_kernel<64, 32><<<dim3((Pt1 + 63) / 64, 27), 256, 0, stream>>>(x2, Wt1, int1, outt1, Pt1, bst1, gridC, flt1, contrib);
        gather_reduce_kernel<32, true><<<gridC, 256, 0, stream>>>(contrib, dpt1, flt1, n1p, xt1, sumst1);
    } else {
        sconv_direct<64, 32, 32, 2><<<gridC, 256, 0, stream>>>(x2, Wt1, int1, outt1, Pt1, n1p, bst1, xt1, sumst1);
    }
    bn_norm_relu_kernel<32><<<480, 256, 0, stream>>>(xt1, n1p, sumst1, gt1, bt1);

    // ---- convtr2: 32 -> 20, no BN ----
    if (csrt2) {
        pair_gemm_kernel<32, 20><<<dim3((Pt2 + 63) / 64, 27), 256, 0, stream>>>(xt1, Wt2, int2, outt2, Pt2, bst2, gridC, flt2, contrib);
        gather_reduce_kernel<20, false><<<gridC, 256, 0, stream>>>(contrib, dpt2, flt2, n0p, out, nullptr);
    } else {
        sconv_direct<32, 20, 32, 1><<<gridC, 256, 0, stream>>>(xt1, Wt2, int2, outt2, Pt2, n0p, bst2, out, nullptr);
    }
}

// Round 13
// 527.914 us; speedup vs baseline: 2.4776x; 1.1287x over previous
//
#include <hip/hip_runtime.h>

// SimpleMinkUNet: 5 sparse convs + 4 training-mode BN+ReLU.
// R13: R12 CSR structure. assign_all (one contended ATOMIC per wave on 4
// adjacent counters -> ~7500 serialized cross-XCD round-trips = 88us, the
// top dispatch) replaced by a deterministic 3-phase exclusive scan:
//  A: per-block degree sums -> bsum;  B: single block scans bsum (per-conv
//  restart);  C: per-block LDS scan + base -> ptr/fill. Zero contention.

constexpr int RT = 64;   // output rows per block

struct SegDesc {
    const int* OO[5];
    const int* np[5];
    int*       bs[5];
    int        P[5];
};

// bsT[r][b*27+k] = lower_bound(OO_r[k], min(b*RT, n_out_r)), b in [0,nblk].
// Row b=nblk == real (non-pad) pair count per k.
// Block 0 zeroes the 4KB BN sums region.
__global__ void seg_all_kernel(SegDesc d, int nblk, double* __restrict__ sums)
{
    if (blockIdx.x == 0) {
        sums[threadIdx.x] = 0.0;
        sums[256 + threadIdx.x] = 0.0;
    }
    int idx = blockIdx.x * blockDim.x + threadIdx.x;
    int per = 27 * (nblk + 1);
    if (idx >= 5 * per) return;
    int r   = idx / per;
    int rem = idx - r * per;
    int k   = rem / (nblk + 1);
    int b   = rem - k * (nblk + 1);
    int n_out = *d.np[r];
    int target = b * RT; if (target > n_out) target = n_out;
    const int* ok = d.OO[r] + (size_t)k * d.P[r];
    int lo = 0, hi = d.P[r];
    while (lo < hi) {
        int mid = (lo + hi) >> 1;
        if (ok[mid] < target) lo = mid + 1; else hi = mid;
    }
    d.bs[r][b * 27 + k] = lo;
}

// ---- CSR pass 1: deg[o] counts (convs 1,2,t1,t2) ----
struct CountDesc {
    const int* OO[4];
    const int* bs[4];
    int*       deg[4];
    int        P[4];
    int        off[5];   // cumulative 27*P
};
__global__ __launch_bounds__(256)
void count_all_kernel(CountDesc d, int nblk)
{
    int idx = blockIdx.x * 256 + threadIdx.x;
    if (idx >= d.off[4]) return;
    int r = 0;
    while (r < 3 && idx >= d.off[r + 1]) ++r;
    int rem = idx - d.off[r];
    int k = rem / d.P[r];
    int j = rem - k * d.P[r];
    int len = d.bs[r][nblk * 27 + k];
    if (j < len)
        atomicAdd(&d.deg[r][d.OO[r][(size_t)k * d.P[r] + j]], 1);
}

// ---- CSR pass 2: deterministic 3-phase exclusive scan (no atomics) ----
struct ScanDesc {
    int*       degptr[4];   // in: deg; out: start (in place)
    int*       fill[4];
    const int* np[4];
};

// Phase A: per-block sums
__global__ __launch_bounds__(256)
void scan_a_kernel(ScanDesc d, int nb, int* __restrict__ bsum)
{
    int r = blockIdx.x / nb;
    int b = blockIdx.x - r * nb;
    int o = b * 256 + threadIdx.x;
    int n = *d.np[r];
    int v = (o < n) ? d.degptr[r][o] : 0;
    __shared__ int ls[256];
    ls[threadIdx.x] = v;
    __syncthreads();
    for (int s = 128; s > 0; s >>= 1) {
        if (threadIdx.x < s) ls[threadIdx.x] += ls[threadIdx.x + s];
        __syncthreads();
    }
    if (threadIdx.x == 0) bsum[blockIdx.x] = ls[0];
}

// Phase B: single block scans bsum, restarting carry at each conv boundary
__global__ __launch_bounds__(256)
void scan_b_kernel(int* __restrict__ bsum, int nb)
{
    __shared__ int ls[256];
    __shared__ int carry;
    const int tid = threadIdx.x;
    for (int r = 0; r < 4; ++r) {
        if (tid == 0) carry = 0;
        __syncthreads();
        for (int c = 0; c < nb; c += 256) {
            int i = c + tid;
            int v = (i < nb) ? bsum[r * nb + i] : 0;
            ls[tid] = v;
            __syncthreads();
            for (int s = 1; s < 256; s <<= 1) {
                int t = (tid >= s) ? ls[tid - s] : 0;
                __syncthreads();
                ls[tid] += t;
                __syncthreads();
            }
            int tot = ls[255];
            int excl = ls[tid] - v;
            if (i < nb) bsum[r * nb + i] = excl + carry;
            __syncthreads();
            if (tid == 0) carry += tot;
            __syncthreads();
        }
    }
}

// Phase C: per-block exclusive scan + base -> ptr/fill
__global__ __launch_bounds__(256)
void scan_c_kernel(ScanDesc d, int nb, const int* __restrict__ bsum)
{
    int r = blockIdx.x / nb;
    int b = blockIdx.x - r * nb;
    int o = b * 256 + threadIdx.x;
    int n = *d.np[r];
    int v = (o < n) ? d.degptr[r][o] : 0;
    __shared__ int ls[256];
    const int tid = threadIdx.x;
    ls[tid] = v;
    __syncthreads();
    for (int s = 1; s < 256; s <<= 1) {
        int t = (tid >= s) ? ls[tid - s] : 0;
        __syncthreads();
        ls[tid] += t;
        __syncthreads();
    }
    int start = ls[tid] - v + bsum[blockIdx.x];
    if (o < n) {
        d.degptr[r][o] = start;
        d.fill[r][o]   = start;
    }
}

// ---- Phase 1: mini-GEMM per (k, 64-pair chunk); claims CSR slot per pair ----
// PB=2 shares each w-quad across 2 pairs; unroll 4 bounds register pressure.
template<int CIN, int COUT>
__global__ __launch_bounds__(256)
void pair_gemm_kernel(const float* __restrict__ F, const float* __restrict__ W,
                      const int* __restrict__ II, const int* __restrict__ OO,
                      int P, const int* __restrict__ bs, int nblk,
                      int* __restrict__ fill, float* __restrict__ contrib)
{
    constexpr int CP    = COUT / 4;
    constexpr int NSLOT = 256 / CP;
    constexpr int CH    = CIN / 4;
    constexpr int FS    = CIN + 4;

    __shared__ __align__(16) float s_w[CIN * COUT];
    __shared__ __align__(16) float s_f[64 * FS];
    __shared__ int s_slot[64];

    const int k   = blockIdx.y;
    const int len = bs[nblk * 27 + k];       // real pair count for this k
    const int j0  = blockIdx.x * 64;
    if (j0 >= len) return;
    const int cnt = min(64, len - j0);
    const int tid = threadIdx.x;

    for (int i = tid; i < CIN * COUT / 4; i += 256)
        ((float4*)s_w)[i] = ((const float4*)(W + (size_t)k * CIN * COUT))[i];
    const int* IIk = II + (size_t)k * P + j0;
    for (int i = tid; i < cnt * CH; i += 256) {
        int p = i / CH, q = i - p * CH;
        int in = IIk[p];
        *(float4*)&s_f[p * FS + q * 4] = ((const float4*)(F + (size_t)in * CIN))[q];
    }
    if (tid < cnt) {                         // distinct o within a k -> no contention
        int o = OO[(size_t)k * P + j0 + tid];
        s_slot[tid] = atomicAdd(&fill[o], 1);
    }
    __syncthreads();

    if (tid >= CP * NSLOT) return;
    const int slot = tid / CP;
    const int cq   = (tid % CP) * 4;

    for (int p0 = slot * 2; p0 < cnt; p0 += NSLOT * 2) {
        const int  p1   = p0 + 1;
        const bool has1 = p1 < cnt;
        const int  p1c  = has1 ? p1 : p0;
        float4 a = make_float4(0.f, 0.f, 0.f, 0.f);
        float4 b = make_float4(0.f, 0.f, 0.f, 0.f);
        #pragma unroll 4
        for (int ci = 0; ci < CIN; ci += 4) {
            float4 w0 = *(const float4*)&s_w[(ci + 0) * COUT + cq];
            float4 w1 = *(const float4*)&s_w[(ci + 1) * COUT + cq];
            float4 w2 = *(const float4*)&s_w[(ci + 2) * COUT + cq];
            float4 w3 = *(const float4*)&s_w[(ci + 3) * COUT + cq];
            float4 f0 = *(const float4*)&s_f[p0  * FS + ci];
            float4 f1 = *(const float4*)&s_f[p1c * FS + ci];
            a.x += f0.x * w0.x + f0.y * w1.x + f0.z * w2.x + f0.w * w3.x;
            a.y += f0.x * w0.y + f0.y * w1.y + f0.z * w2.y + f0.w * w3.y;
            a.z += f0.x * w0.z + f0.y * w1.z + f0.z * w2.z + f0.w * w3.z;
            a.w += f0.x * w0.w + f0.y * w1.w + f0.z * w2.w + f0.w * w3.w;
            b.x += f1.x * w0.x + f1.y * w1.x + f1.z * w2.x + f1.w * w3.x;
            b.y += f1.x * w0.y + f1.y * w1.y + f1.z * w2.y + f1.w * w3.y;
            b.z += f1.x * w0.z + f1.y * w1.z + f1.z * w2.z + f1.w * w3.z;
            b.w += f1.x * w0.w + f1.y * w1.w + f1.z * w2.w + f1.w * w3.w;
        }
        *(float4*)&contrib[(size_t)s_slot[p0] * COUT + cq] = a;
        if (has1)
            *(float4*)&contrib[(size_t)s_slot[p1] * COUT + cq] = b;
    }
}

// ---- Phase 2: stream each output's contiguous contrib run; fused BN ----
template<int COUT, bool BN>
__global__ __launch_bounds__(256)
void gather_reduce_kernel(const float* __restrict__ contrib,
                          const int* __restrict__ ptr_,
                          const int* __restrict__ fill_,
                          const int* __restrict__ n_out_ptr,
                          float* __restrict__ OUT, double* __restrict__ sums)
{
    constexpr int CP = COUT / 4;
    constexpr int NG = 256 / CP;
    constexpr int ROUNDS = (RT + NG - 1) / NG;

    __shared__ float s_bn[BN ? 2 * COUT : 1];

    const int n_out = *n_out_ptr;
    const int row0 = blockIdx.x * RT;
    if (row0 >= n_out) return;
    const int tid = threadIdx.x;
    const int grp = tid / CP;
    const int cq  = (tid % CP) * 4;

    float4 bsum = make_float4(0.f, 0.f, 0.f, 0.f);
    float4 bsq  = make_float4(0.f, 0.f, 0.f, 0.f);

    #pragma unroll
    for (int r = 0; r < ROUNDS; ++r) {
        int og = grp + r * NG;
        int o  = row0 + og;
        if (grp < NG && og < RT && o < n_out) {
            int t0 = ptr_[o], t1 = fill_[o];
            float4 a = make_float4(0.f, 0.f, 0.f, 0.f);
            for (int t = t0; t < t1; ++t) {
                float4 v = *(const float4*)&contrib[(size_t)t * COUT + cq];
                a.x += v.x; a.y += v.y; a.z += v.z; a.w += v.w;
            }
            *(float4*)&OUT[(size_t)o * COUT + cq] = a;
            if (BN) {
                bsum.x += a.x; bsum.y += a.y; bsum.z += a.z; bsum.w += a.w;
                bsq.x += a.x * a.x; bsq.y += a.y * a.y;
                bsq.z += a.z * a.z; bsq.w += a.w * a.w;
            }
        }
    }
    if (BN) {
        if (tid < 2 * COUT) s_bn[tid] = 0.f;
        __syncthreads();
        atomicAdd(&s_bn[cq + 0], bsum.x); atomicAdd(&s_bn[cq + 1], bsum.y);
        atomicAdd(&s_bn[cq + 2], bsum.z); atomicAdd(&s_bn[cq + 3], bsum.w);
        atomicAdd(&s_bn[COUT + cq + 0], bsq.x); atomicAdd(&s_bn[COUT + cq + 1], bsq.y);
        atomicAdd(&s_bn[COUT + cq + 2], bsq.z); atomicAdd(&s_bn[COUT + cq + 3], bsq.w);
        __syncthreads();
        if (tid < COUT) {
            atomicAdd(&sums[tid], (double)s_bn[tid]);
            atomicAdd(&sums[COUT + tid], (double)s_bn[COUT + tid]);
        }
    }
}

// ---- conv0 direct: CIN=4, COUT=16 (flat build + flat pair loop) ----
__device__ __forceinline__ int find_seg(const int* s_off, int p)
{
    int k = 0;
    #pragma unroll
    for (int st = 16; st; st >>= 1)
        if (k + st < 28 && s_off[k + st] <= p) k += st;
    return k;
}

__global__ __launch_bounds__(256)
void sconv0_kernel(const float* __restrict__ F, const float* __restrict__ W,
                   const int* __restrict__ II, const int* __restrict__ OO,
                   int P, const int* __restrict__ n_out_ptr,
                   const int* __restrict__ bs,
                   float* __restrict__ OUT, double* __restrict__ sums)
{
    constexpr int CIN = 4, COUT = 16, CP = 16, NSLOT = 16;

    __shared__ float    s_acc[RT * COUT];
    __shared__ unsigned s_pair[27 * RT];
    __shared__ int s_s[27], s_off[28];

    const int n_out = *n_out_ptr;
    const int row0 = blockIdx.x * RT;
    if (row0 >= n_out) return;
    const int tid = threadIdx.x;

    if (tid < 27) {
        int s = bs[blockIdx.x * 27 + tid];
        int e = bs[(blockIdx.x + 1) * 27 + tid];
        s_s[tid] = s;
        s_off[tid + 1] = e - s;
    }
    if (tid == 0) s_off[0] = 0;
    for (int i = tid; i < RT * COUT; i += 256) s_acc[i] = 0.f;
    __syncthreads();
    if (tid == 0) for (int k = 1; k <= 27; ++k) s_off[k] += s_off[k - 1];
    __syncthreads();
    const int npairs = s_off[27];

    for (int idx = tid; idx < npairs; idx += 256) {
        int k = find_seg(s_off, idx);
        int j = s_s[k] + (idx - s_off[k]);
        int o  = OO[(size_t)k * P + j] - row0;
        int in = II[(size_t)k * P + j];
        s_pair[idx] = ((unsigned)in << 11) | ((unsigned)k << 6) | (unsigned)o;
    }
    __syncthreads();

    const int slot = tid / CP, c = tid % CP;
    for (int p = slot; p < npairs; p += NSLOT) {
        unsigned v = s_pair[p];
        int o = v & 63, k = (v >> 6) & 31;
        float4 f = *(const float4*)(F + (size_t)(v >> 11) * CIN);
        const float* w = W + k * (CIN * COUT) + c;
        float a = f.x * w[0] + f.y * w[COUT] + f.z * w[2 * COUT] + f.w * w[3 * COUT];
        atomicAdd(&s_acc[o * COUT + c], a);
    }
    __syncthreads();

    const int rows = min(RT, n_out - row0);
    {
        const int nel4 = rows * COUT / 4;
        float4* dst = (float4*)(OUT + (size_t)row0 * COUT);
        for (int i = tid; i < nel4; i += 256) dst[i] = ((const float4*)s_acc)[i];
    }
    if (sums != nullptr) {
        float* red = (float*)s_pair;
        const int ch = tid % COUT;
        float s = 0.f, s2 = 0.f;
        for (int r = tid / COUT; r < rows; r += 256 / COUT) {
            float v = s_acc[r * COUT + ch];
            s += v; s2 += v * v;
        }
        red[tid] = s; red[256 + tid] = s2;
        __syncthreads();
        if (tid < COUT) {
            for (int j = tid + COUT; j < 256; j += COUT) { s += red[j]; s2 += red[256 + j]; }
            atomicAdd(&sums[tid], (double)s);
            atomicAdd(&sums[COUT + tid], (double)s2);
        }
    }
}

// ---- direct sconv fallback (R6 structure, bsT layout) ----
template<int CIN, int COUT, int CP, int KS>
__global__ __launch_bounds__(256, 4)
void sconv_direct(const float* __restrict__ F, const float* __restrict__ W,
                  const int* __restrict__ II, const int* __restrict__ OO,
                  int P, const int* __restrict__ n_out_ptr,
                  const int* __restrict__ bs,
                  float* __restrict__ OUT, double* __restrict__ sums)
{
    constexpr int SL    = CP * KS;
    constexpr int NSLOT = 256 / SL;
    constexpr int CINL  = CIN / KS;
    constexpr int NF4   = CINL / 4;

    __shared__ float    s_acc[RT * COUT];
    __shared__ unsigned s_pair[27 * RT];
    __shared__ int s_s[27], s_off[28];

    const int n_out = *n_out_ptr;
    const int row0 = blockIdx.x * RT;
    if (row0 >= n_out) return;
    const int tid = threadIdx.x;

    if (tid < 27) {
        int s = bs[blockIdx.x * 27 + tid];
        int e = bs[(blockIdx.x + 1) * 27 + tid];
        s_s[tid] = s;
        s_off[tid + 1] = e - s;
    }
    if (tid == 0) s_off[0] = 0;
    for (int i = tid; i < RT * COUT; i += 256) s_acc[i] = 0.f;
    __syncthreads();
    if (tid == 0) for (int k = 1; k <= 27; ++k) s_off[k] += s_off[k - 1];
    __syncthreads();
    const int npairs = s_off[27];

    for (int idx = tid; idx < npairs; idx += 256) {
        int k = find_seg(s_off, idx);
        int j = s_s[k] + (idx - s_off[k]);
        int o  = OO[(size_t)k * P + j] - row0;
        int in = II[(size_t)k * P + j];
        s_pair[idx] = ((unsigned)in << 11) | (unsigned)o;
    }
    __syncthreads();

    const int slot = tid / SL;
    const int lc   = tid % CP;
    const int ksub = (tid % SL) / CP;
    const int c    = (CP > COUT && lc >= COUT) ? (COUT - 1) : lc;
    const bool cok = (CP <= COUT) || (lc < COUT);

    for (int k = 0; k < 27; ++k) {
        const int off = s_off[k], end = s_off[k + 1];
        if (off == end) continue;

        float wreg[CINL];
        const float* Wk = W + k * (CIN * COUT) + (ksub * CINL) * COUT + c;
        #pragma unroll
        for (int i = 0; i < CINL; ++i) wreg[i] = Wk[i * COUT];

        for (int base2 = off + 2 * slot; base2 < end; base2 += 2 * NSLOT) {
            unsigned v0 = s_pair[base2];
            const bool has1 = (base2 + 1) < end;
            unsigned v1 = has1 ? s_pair[base2 + 1] : v0;
            const float* F0 = F + (size_t)(v0 >> 11) * CIN + ksub * CINL;
            const float* F1 = F + (size_t)(v1 >> 11) * CIN + ksub * CINL;
            float4 f0[NF4], f1[NF4];
            #pragma unroll
            for (int i = 0; i < NF4; ++i) f0[i] = ((const float4*)F0)[i];
            #pragma unroll
            for (int i = 0; i < NF4; ++i) f1[i] = ((const float4*)F1)[i];
            float a0 = 0.f, a1 = 0.f, a2 = 0.f, a3 = 0.f;
            float b0 = 0.f, b1 = 0.f, b2 = 0.f, b3 = 0.f;
            #pragma unroll
            for (int i = 0; i < NF4; ++i) {
                a0 += f0[i].x * wreg[4*i+0]; a1 += f0[i].y * wreg[4*i+1];
                a2 += f0[i].z * wreg[4*i+2]; a3 += f0[i].w * wreg[4*i+3];
                b0 += f1[i].x * wreg[4*i+0]; b1 += f1[i].y * wreg[4*i+1];
                b2 += f1[i].z * wreg[4*i+2]; b3 += f1[i].w * wreg[4*i+3];
            }
            if (cok) {
                atomicAdd(&s_acc[(v0 & 63) * COUT + c], (a0 + a1) + (a2 + a3));
                if (has1)
                    atomicAdd(&s_acc[(v1 & 63) * COUT + c], (b0 + b1) + (b2 + b3));
            }
        }
    }
    __syncthreads();

    const int rows = min(RT, n_out - row0);
    {
        const int nel4 = rows * COUT / 4;
        float4* dst = (float4*)(OUT + (size_t)row0 * COUT);
        for (int i = tid; i < nel4; i += 256) dst[i] = ((const float4*)s_acc)[i];
    }
    if (sums != nullptr) {
        float* red = (float*)s_pair;
        const int ch = tid % COUT;
        float s = 0.f, s2 = 0.f;
        for (int r = tid / COUT; r < rows; r += 256 / COUT) {
            float v = s_acc[r * COUT + ch];
            s += v; s2 += v * v;
        }
        red[tid] = s; red[256 + tid] = s2;
        __syncthreads();
        if (tid < COUT) {
            for (int j = tid + COUT; j < 256; j += COUT) { s += red[j]; s2 += red[256 + j]; }
            atomicAdd(&sums[tid], (double)s);
            atomicAdd(&sums[COUT + tid], (double)s2);
        }
    }
}

// ---- normalize + ReLU in place ----
template<int COUT>
__global__ void bn_norm_relu_kernel(float* __restrict__ X, const int* __restrict__ n_ptr,
                                    const double* __restrict__ sums,
                                    const float* __restrict__ gamma,
                                    const float* __restrict__ beta)
{
    constexpr int G = 256 / COUT;
    const int n = *n_ptr;
    const int tid = threadIdx.x;
    const int c = tid % COUT;
    const int g = tid / COUT;
    double m  = sums[c] / n;
    double vv = sums[COUT + c] / n - m * m;
    float inv = (float)rsqrt(vv + 1e-5);
    float scale = inv * gamma[c];
    float off = beta[c] - (float)m * scale;
    for (int r = blockIdx.x * G + g; r < n; r += gridDim.x * G) {
        float v = X[r * COUT + c] * scale + off;
        X[r * COUT + c] = v > 0.f ? v : 0.f;
    }
}

extern "C" void kernel_launch(void* const* d_in, const int* in_sizes, int n_in,
                              void* d_out, int out_size, void* d_ws, size_t ws_size,
                              hipStream_t stream)
{
    const float* feats = (const float*)d_in[0];
    const float* W0  = (const float*)d_in[1];
    const float* g0  = (const float*)d_in[2];
    const float* b0  = (const float*)d_in[3];
    const float* W1  = (const float*)d_in[4];
    const float* g1  = (const float*)d_in[5];
    const float* b1  = (const float*)d_in[6];
    const float* W2  = (const float*)d_in[7];
    const float* g2  = (const float*)d_in[8];
    const float* b2  = (const float*)d_in[9];
    const float* Wt1 = (const float*)d_in[10];
    const float* gt1 = (const float*)d_in[11];
    const float* bt1 = (const float*)d_in[12];
    const float* Wt2 = (const float*)d_in[13];
    const int* in0  = (const int*)d_in[14];
    const int* out0 = (const int*)d_in[15];
    const int* in1  = (const int*)d_in[16];
    const int* out1 = (const int*)d_in[17];
    const int* in2  = (const int*)d_in[18];
    const int* out2 = (const int*)d_in[19];
    const int* int1 = (const int*)d_in[20];
    const int* outt1= (const int*)d_in[21];
    const int* int2 = (const int*)d_in[22];
    const int* outt2= (const int*)d_in[23];
    const int* n0p = (const int*)d_in[24];
    const int* n1p = (const int*)d_in[25];
    const int* n2p = (const int*)d_in[26];

    const int n0  = in_sizes[0] / 4;
    const int P0  = in_sizes[14] / 27;
    const int P1  = in_sizes[16] / 27;
    const int P2  = in_sizes[18] / 27;
    const int Pt1 = in_sizes[20] / 27;
    const int Pt2 = in_sizes[22] / 27;

    const int gridC = (n0 + RT - 1) / RT;
    const int nbs = 27 * (gridC + 1);
    const int nb0 = (n0 + 255) / 256;

    // workspace layout:
    //   [0,4096)      BN double sums (zeroed by seg_all blk0)
    //   +4096         bsum (4*nb0 ints, scan scratch)
    //   then degptr[4][n0]  [memset 0]
    //   then fill[4][n0]
    //   then x1 (n0*32), x2 (n0*64)  [x0 aliases x2, xt1 aliases x1]
    //   then bsT x5
    //   then contrib (CSR)
    char* ws = (char*)d_ws;
    double* sums0  = (double*)(ws + 0);
    double* sums1  = (double*)(ws + 1024);
    double* sums2  = (double*)(ws + 2048);
    double* sumst1 = (double*)(ws + 3072);
    int* bsum     = (int*)(ws + 4096);
    int* degbase  = bsum + 4 * (size_t)nb0;
    int* dp1 = degbase, *dp2 = degbase + n0, *dpt1 = degbase + 2*n0, *dpt2 = degbase + 3*n0;
    int* fillbase = degbase + 4 * (size_t)n0;
    int* fl1 = fillbase, *fl2 = fillbase + n0, *flt1 = fillbase + 2*n0, *flt2 = fillbase + 3*n0;
    float* x1  = (float*)(fillbase + 4 * (size_t)n0);
    float* x2  = x1 + (size_t)n0 * 32;
    float* x0  = x2;                       // aliases x2 (dead before x2 written)
    float* xt1 = x1;                       // aliases x1 (dead before xt1 written)
    int* bs0  = (int*)(x2 + (size_t)n0 * 64);
    int* bs1  = bs0 + nbs;
    int* bs2  = bs1 + nbs;
    int* bst1 = bs2 + nbs;
    int* bst2 = bst1 + nbs;
    float* out = (float*)d_out;

    size_t base = (size_t)((char*)(bst2 + nbs) - ws);
    base = (base + 255) & ~(size_t)255;
    float* contrib = (float*)(ws + base);
    size_t avail = (ws_size > base) ? (ws_size - base) : 0;

    auto fits = [&](int P, int C) -> bool {
        return (size_t)27 * P * C * 4 <= avail;
    };
    const bool csr1  = fits(P1, 32);
    const bool csr2  = fits(P2, 64);
    const bool csrt1 = fits(Pt1, 32);
    const bool csrt2 = fits(Pt2, 20);

    hipMemsetAsync(degbase, 0, (size_t)4 * n0 * 4, stream);

    SegDesc sd;
    sd.OO[0] = out0;  sd.np[0] = n0p; sd.bs[0] = bs0;  sd.P[0] = P0;
    sd.OO[1] = out1;  sd.np[1] = n1p; sd.bs[1] = bs1;  sd.P[1] = P1;
    sd.OO[2] = out2;  sd.np[2] = n2p; sd.bs[2] = bs2;  sd.P[2] = P2;
    sd.OO[3] = outt1; sd.np[3] = n1p; sd.bs[3] = bst1; sd.P[3] = Pt1;
    sd.OO[4] = outt2; sd.np[4] = n0p; sd.bs[4] = bst2; sd.P[4] = Pt2;
    seg_all_kernel<<<(5 * nbs + 255) / 256, 256, 0, stream>>>(sd, gridC, (double*)ws);

    CountDesc cd;
    cd.OO[0] = out1;  cd.bs[0] = bs1;  cd.deg[0] = dp1;  cd.P[0] = P1;
    cd.OO[1] = out2;  cd.bs[1] = bs2;  cd.deg[1] = dp2;  cd.P[1] = P2;
    cd.OO[2] = outt1; cd.bs[2] = bst1; cd.deg[2] = dpt1; cd.P[2] = Pt1;
    cd.OO[3] = outt2; cd.bs[3] = bst2; cd.deg[3] = dpt2; cd.P[3] = Pt2;
    cd.off[0] = 0;
    cd.off[1] = 27 * P1;
    cd.off[2] = cd.off[1] + 27 * P2;
    cd.off[3] = cd.off[2] + 27 * Pt1;
    cd.off[4] = cd.off[3] + 27 * Pt2;
    count_all_kernel<<<(cd.off[4] + 255) / 256, 256, 0, stream>>>(cd, gridC);

    ScanDesc scd;
    scd.degptr[0] = dp1;  scd.fill[0] = fl1;  scd.np[0] = n1p;
    scd.degptr[1] = dp2;  scd.fill[1] = fl2;  scd.np[1] = n2p;
    scd.degptr[2] = dpt1; scd.fill[2] = flt1; scd.np[2] = n1p;
    scd.degptr[3] = dpt2; scd.fill[3] = flt2; scd.np[3] = n0p;
    scan_a_kernel<<<4 * nb0, 256, 0, stream>>>(scd, nb0, bsum);
    scan_b_kernel<<<1, 256, 0, stream>>>(bsum, nb0);
    scan_c_kernel<<<4 * nb0, 256, 0, stream>>>(scd, nb0, bsum);

    // ---- conv0: 4 -> 16 (direct) ----
    sconv0_kernel<<<gridC, 256, 0, stream>>>(feats, W0, in0, out0, P0, n0p, bs0, x0, sums0);
    bn_norm_relu_kernel<16><<<480, 256, 0, stream>>>(x0, n0p, sums0, g0, b0);

    // ---- conv1: 16 -> 32 ----
    if (csr1) {
        pair_gemm_kernel<16, 32><<<dim3((P1 + 63) / 64, 27), 256, 0, stream>>>(x0, W1, in1, out1, P1, bs1, gridC, fl1, contrib);
        gather_reduce_kernel<32, true><<<gridC, 256, 0, stream>>>(contrib, dp1, fl1, n1p, x1, sums1);
    } else {
        sconv_direct<16, 32, 32, 1><<<gridC, 256, 0, stream>>>(x0, W1, in1, out1, P1, n1p, bs1, x1, sums1);
    }
    bn_norm_relu_kernel<32><<<480, 256, 0, stream>>>(x1, n1p, sums1, g1, b1);

    // ---- conv2: 32 -> 64 ----
    if (csr2) {
        pair_gemm_kernel<32, 64><<<dim3((P2 + 63) / 64, 27), 256, 0, stream>>>(x1, W2, in2, out2, P2, bs2, gridC, fl2, contrib);
        gather_reduce_kernel<64, true><<<gridC, 256, 0, stream>>>(contrib, dp2, fl2, n2p, x2, sums2);
    } else {
        sconv_direct<32, 64, 64, 1><<<gridC, 256, 0, stream>>>(x1, W2, in2, out2, P2, n2p, bs2, x2, sums2);
    }
    bn_norm_relu_kernel<64><<<480, 256, 0, stream>>>(x2, n2p, sums2, g2, b2);

    // ---- convtr1: 64 -> 32 ----
    if (csrt1) {
        pair_gemm_kernel<64, 32><<<dim3((Pt1 + 63) / 64, 27), 256, 0, stream>>>(x2, Wt1, int1, outt1, Pt1, bst1, gridC, flt1, contrib);
        gather_reduce_kernel<32, true><<<gridC, 256, 0, stream>>>(contrib, dpt1, flt1, n1p, xt1, sumst1);
    } else {
        sconv_direct<64, 32, 32, 2><<<gridC, 256, 0, stream>>>(x2, Wt1, int1, outt1, Pt1, n1p, bst1, xt1, sumst1);
    }
    bn_norm_relu_kernel<32><<<480, 256, 0, stream>>>(xt1, n1p, sumst1, gt1, bt1);

    // ---- convtr2: 32 -> 20, no BN ----
    if (csrt2) {
        pair_gemm_kernel<32, 20><<<dim3((Pt2 + 63) / 64, 27), 256, 0, stream>>>(xt1, Wt2, int2, outt2, Pt2, bst2, gridC, flt2, contrib);
        gather_reduce_kernel<20, false><<<gridC, 256, 0, stream>>>(contrib, dpt2, flt2, n0p, out, nullptr);
    } else {
        sconv_direct<32, 20, 32, 1><<<gridC, 256, 0, stream>>>(xt1, Wt2, int2, outt2, Pt2, n0p, bst2, out, nullptr);
    }
}